// Round 8
// baseline (1647.930 us; speedup 1.0000x reference)
//
#include <hip/hip_runtime.h>

#define T_TOK 4096
#define H_DIM 2048
#define I_DIM 5632
#define NE 8

typedef _Float16 f16;
typedef _Float16 f16x8 __attribute__((ext_vector_type(8)));
typedef _Float16 f16x4 __attribute__((ext_vector_type(4)));
typedef float f32x4 __attribute__((ext_vector_type(4)));

// ---- workspace layout (byte offsets) ----
#define OFF_META   0                         // counts[8] | offs[8] | cursor[8]
#define OFF_BTOK   256
#define OFF_BW     (256 + 32768)
#define OFF_RE     (256 + 2 * 32768)
#define OFF_RW     (256 + 3 * 32768)
#define OFF_HSB    (256 + 4 * 32768)
#define OFF_HB     (OFF_HSB + (size_t)T_TOK * H_DIM * 2)

typedef const __attribute__((address_space(1))) unsigned int guint;
typedef __attribute__((address_space(3))) unsigned int luint;

// manual waits: vmcnt(8) after MFMA cluster retires the A-DMA (leaves 8 B-loads in
// flight); lgkmcnt(0)+sched_barrier(0) fences ds_read results before MFMA (rule #18).
#define WAITVM8()   asm volatile("s_waitcnt vmcnt(8)" ::: "memory")
#define WAITVM0()   asm volatile("s_waitcnt vmcnt(0)" ::: "memory")
#define LGKM0_SB()  do { asm volatile("s_waitcnt lgkmcnt(0)" ::: "memory"); __builtin_amdgcn_sched_barrier(0); } while (0)

// 8-slot (16B) XOR swizzle within a 128-byte LDS row: conflict-free reads (verified R3-R7: 0 conflicts)
__device__ __forceinline__ int swzk(int r, int bir) {
    return (bir & 15) | ((((bir >> 4) ^ r) & 7) << 4);
}

__device__ __forceinline__ f16x4 cvt4(float4 v) {
    f16x4 t; t[0] = (f16)v.x; t[1] = (f16)v.y; t[2] = (f16)v.z; t[3] = (f16)v.w; return t;
}

__device__ __forceinline__ f16x8 ldsr(const char* base, int r, int kb) {
    return *(const f16x8*)(base + r * 128 + swzk(r, kb));
}

// ---------------- hs f32 -> f16 ----------------
__global__ void cvt_hs_kernel(const float* __restrict__ hs, f16* __restrict__ hsb) {
    size_t i = ((size_t)blockIdx.x * 256 + threadIdx.x) * 8;
    float4 a = *(const float4*)(hs + i);
    float4 b = *(const float4*)(hs + i + 4);
    f16x8 v;
    v[0] = (f16)a.x; v[1] = (f16)a.y; v[2] = (f16)a.z; v[3] = (f16)a.w;
    v[4] = (f16)b.x; v[5] = (f16)b.y; v[6] = (f16)b.z; v[7] = (f16)b.w;
    *(f16x8*)(hsb + i) = v;
}

// ---------------- gating ----------------
__global__ void gate_kernel(const float* __restrict__ hs, const float* __restrict__ gw,
                            int* __restrict__ re, float* __restrict__ rw,
                            int* __restrict__ counts) {
    int lane = threadIdx.x & 63;
    int t = blockIdx.x * 4 + (threadIdx.x >> 6);
    float acc[NE];
#pragma unroll
    for (int e = 0; e < NE; ++e) acc[e] = 0.f;
    const float* x = hs + (size_t)t * H_DIM;
    for (int i = lane; i < H_DIM; i += 64) {
        float xv = x[i];
#pragma unroll
        for (int e = 0; e < NE; ++e) acc[e] += xv * gw[e * H_DIM + i];
    }
#pragma unroll
    for (int e = 0; e < NE; ++e)
        for (int off = 32; off > 0; off >>= 1) acc[e] += __shfl_xor(acc[e], off);
    if (lane == 0) {
        int i1 = 0; float l1 = acc[0];
#pragma unroll
        for (int e = 1; e < NE; ++e) if (acc[e] > l1) { l1 = acc[e]; i1 = e; }
        int i2 = -1; float l2 = -1e30f;
#pragma unroll
        for (int e = 0; e < NE; ++e) if (e != i1 && acc[e] > l2) { l2 = acc[e]; i2 = e; }
        float aa = __expf(l2 - l1);
        float s = 1.f / (1.f + aa);
        re[t * 2] = i1; re[t * 2 + 1] = i2;
        rw[t * 2] = s;  rw[t * 2 + 1] = aa * s;
        atomicAdd(&counts[i1], 1);
        atomicAdd(&counts[i2], 1);
    }
}

__global__ void scan_kernel(int* __restrict__ meta) {
    if (threadIdx.x == 0) {
        int s = 0;
        for (int e = 0; e < NE; ++e) { meta[8 + e] = s; meta[16 + e] = s; s += meta[e]; }
    }
}

__global__ void place_kernel(const int* __restrict__ re, const float* __restrict__ rw,
                             int* __restrict__ cursor, int* __restrict__ btok,
                             float* __restrict__ bwv) {
    int t = blockIdx.x * 256 + threadIdx.x;
    if (t >= T_TOK) return;
#pragma unroll
    for (int s = 0; s < 2; ++s) {
        int e = re[t * 2 + s];
        int p = atomicAdd(&cursor[e], 1);
        btok[p] = t;
        bwv[p] = rw[t * 2 + s];
    }
}

// Panel-pinned XCD decode (validated R3/R4): panel P = sg*8 + (id&7) lives entirely on
// XCD id%8; its 32 by-blocks are contiguous ids there. Requires total panels % 8 == 0.
__device__ __forceinline__ void decode_panel(int id, int npx, int e_arg,
                                             int& e, int& bx, int& by) {
    if (e_arg >= 0) { e = e_arg; bx = id >> 5; by = id & 31; return; }
    int sg  = id >> 8;
    int rem = id & 255;
    by = rem >> 3;
    int P = sg * 8 + (rem & 7);
    e = P / npx; bx = P % npx;
}

// ---------------- GEMM1: h = silu(X@Wg^T) * (X@Wu^T) ----------------
// m201-template port: BM=128 tokens, BN=256 weight rows (128 g | 128 u => 128 h-cols),
// BK=64, 512 thr / 8 waves (2M x 4N), per-wave 64 rows x (32 g + 32 u) = 64 acc VGPR.
// Per K-tile: 2 phases {prefetch-issue; 12 ds_read; cvt+ds_write B-half; barrier;
// lgkm0; setprio1; 16 MFMA; setprio0; barrier}. B reg-staged 2 tiles deep;
// A via global_load_lds double-buffered; one vmcnt(8) per tile after the MFMAs.
__global__ __launch_bounds__(512, 2) void gemm1_kernel(
    const float* __restrict__ w13, const f16* __restrict__ hsb, f16* __restrict__ hb,
    const int* __restrict__ counts, const int* __restrict__ offs,
    const int* __restrict__ btok, int e_arg, int global_h)
{
    int e, bx, by;
    decode_panel(blockIdx.x, 44, e_arg, e, bx, by);
    const int n_e = counts[e];
    if (by * 128 >= n_e) return;
    const int boff = offs[e];
    const float* We = w13 + (size_t)e * (2 * I_DIM) * H_DIM;

    const int tid  = threadIdx.x;
    const int lane = tid & 63;
    const int wid  = tid >> 6;
    const int wm   = wid >> 2;          // 0..1
    const int wn   = wid & 3;           // 0..3
    const int l15  = lane & 15;
    const int klo  = (lane >> 4) * 16;

    __shared__ f16 As[2][128 * 64];     // 16 KB per buffer
    __shared__ f16 Bs[2][256 * 64];     // 32 KB per buffer (rows 0-127 g, 128-255 u)
    char* AsB = (char*)As; char* BsB = (char*)Bs;

    // A via global_load_lds: chunk c = i*512+tid -> row c>>3, LDS slot c&7 (linear dest),
    // global k-slot (c&7)^(r&7) = inverse swizzle (verified R5).
    const f16* gA[2];
    int adst[2];
#pragma unroll
    for (int i = 0; i < 2; ++i) {
        int c = i * 512 + tid;
        int r = c >> 3;
        int idx = by * 128 + r;
        idx = idx < n_e ? idx : n_e - 1;
        int tok = btok[boff + idx];
        gA[i] = hsb + (size_t)tok * H_DIM + ((c & 7) ^ (r & 7)) * 8;
        adst[i] = c * 16;
    }
    // B: 8 float4/thread per K-tile. chunk c = j*512+tid: LDS row c>>4 (0..255), quad c&15.
    const float* gB[8];
    int bwadr[8];
#pragma unroll
    for (int j = 0; j < 8; ++j) {
        int c = j * 512 + tid;
        int row = c >> 4;
        int k4 = c & 15;
        int wrow = (row < 128) ? (bx * 128 + row) : (I_DIM + bx * 128 + (row - 128));
        gB[j] = We + (size_t)wrow * H_DIM + k4 * 4;
        bwadr[j] = row * 128 + swzk(row, k4 * 8);
    }

    f32x4 ag[4][2], au[4][2];
#pragma unroll
    for (int m = 0; m < 4; ++m)
#pragma unroll
        for (int n = 0; n < 2; ++n) { ag[m][n] = (f32x4)0.f; au[m][n] = (f32x4)0.f; }

    const int NT = H_DIM / 64;   // 32

    float4 bX[4], bY[4];
    // ---- prologue: A[0] DMA -> buf0; B[0] regs -> LDS buf0; issue B[1] regs ----
#pragma unroll
    for (int i = 0; i < 2; ++i)
        __builtin_amdgcn_global_load_lds((guint*)gA[i], (luint*)(AsB + adst[i]), 16, 0, 0);
#pragma unroll
    for (int j = 0; j < 4; ++j) bX[j] = *(const float4*)gB[j];
#pragma unroll
    for (int j = 0; j < 4; ++j) bY[j] = *(const float4*)gB[j + 4];
#pragma unroll
    for (int j = 0; j < 4; ++j) *(f16x4*)(BsB + bwadr[j])     = cvt4(bX[j]);
#pragma unroll
    for (int j = 0; j < 4; ++j) *(f16x4*)(BsB + bwadr[j + 4]) = cvt4(bY[j]);
#pragma unroll
    for (int j = 0; j < 4; ++j) bX[j] = *(const float4*)(gB[j] + 64);
#pragma unroll
    for (int j = 0; j < 4; ++j) bY[j] = *(const float4*)(gB[j + 4] + 64);
    asm volatile("s_waitcnt lgkmcnt(0)" ::: "memory");
    __builtin_amdgcn_s_barrier();

#pragma unroll 1
    for (int kt = 0; kt < NT; ++kt) {
        const int cur = kt & 1;
        const int kA = ((kt + 1 < NT) ? kt + 1 : NT - 1) * 64;
        const int kB = ((kt + 2 < NT) ? kt + 2 : NT - 1) * 64;
        const char* Ab = AsB + cur * 16384;
        const char* Bb = BsB + cur * 32768;
        char* Aw = AsB + (cur ^ 1) * 16384;
        char* Bw = BsB + (cur ^ 1) * 32768;
        // ================= phase 1: g-half =================
        {
#pragma unroll
            for (int i = 0; i < 2; ++i)
                __builtin_amdgcn_global_load_lds((guint*)(gA[i] + kA), (luint*)(Aw + adst[i]), 16, 0, 0);
            f16x8 af[2][4], bf[2][2];
#pragma unroll
            for (int kh = 0; kh < 2; ++kh) {
                const int kb = kh * 64 + klo;
#pragma unroll
                for (int mf = 0; mf < 4; ++mf) af[kh][mf] = ldsr(Ab, wm * 64 + mf * 16 + l15, kb);
#pragma unroll
                for (int nf = 0; nf < 2; ++nf) bf[kh][nf] = ldsr(Bb, wn * 32 + nf * 16 + l15, kb);
            }
            // stage g-half of B[kt+1] (compiler auto-waits the bX register loads)
#pragma unroll
            for (int j = 0; j < 4; ++j) *(f16x4*)(Bw + bwadr[j]) = cvt4(bX[j]);
            __builtin_amdgcn_s_barrier();
            LGKM0_SB();
            __builtin_amdgcn_s_setprio(1);
#pragma unroll
            for (int kh = 0; kh < 2; ++kh)
#pragma unroll
                for (int mf = 0; mf < 4; ++mf)
#pragma unroll
                    for (int nf = 0; nf < 2; ++nf)
                        ag[mf][nf] = __builtin_amdgcn_mfma_f32_16x16x32_f16(af[kh][mf], bf[kh][nf], ag[mf][nf], 0, 0, 0);
            __builtin_amdgcn_s_setprio(0);
            __builtin_amdgcn_s_barrier();
        }
        // ================= phase 2: u-half =================
        {
#pragma unroll
            for (int j = 0; j < 4; ++j) bX[j] = *(const float4*)(gB[j] + kB);      // issue B[kt+2] g-half
            f16x8 af[2][4], bf[2][2];
#pragma unroll
            for (int kh = 0; kh < 2; ++kh) {
                const int kb = kh * 64 + klo;
#pragma unroll
                for (int mf = 0; mf < 4; ++mf) af[kh][mf] = ldsr(Ab, wm * 64 + mf * 16 + l15, kb);
#pragma unroll
                for (int nf = 0; nf < 2; ++nf) bf[kh][nf] = ldsr(Bb, 128 + wn * 32 + nf * 16 + l15, kb);
            }
#pragma unroll
            for (int j = 0; j < 4; ++j) *(f16x4*)(Bw + bwadr[j + 4]) = cvt4(bY[j]); // stage u-half of B[kt+1]
#pragma unroll
            for (int j = 0; j < 4; ++j) bY[j] = *(const float4*)(gB[j + 4] + kB);   // issue B[kt+2] u-half
            __builtin_amdgcn_s_barrier();
            LGKM0_SB();
            __builtin_amdgcn_s_setprio(1);
#pragma unroll
            for (int kh = 0; kh < 2; ++kh)
#pragma unroll
                for (int mf = 0; mf < 4; ++mf)
#pragma unroll
                    for (int nf = 0; nf < 2; ++nf)
                        au[mf][nf] = __builtin_amdgcn_mfma_f32_16x16x32_f16(af[kh][mf], bf[kh][nf], au[mf][nf], 0, 0, 0);
            __builtin_amdgcn_s_setprio(0);
            WAITVM8();                    // retire A[kt+1] DMA; 8 B[kt+2] loads stay in flight
            __builtin_amdgcn_s_barrier(); // tile end: buf[cur^1] fully staged for kt+1
        }
    }
    WAITVM0();   // drain clamped tail DMAs before block exit

    // epilogue: silu(g)*u -> f16 h
    const int hbase = (global_h ? boff : 0) + by * 128;
#pragma unroll
    for (int mf = 0; mf < 4; ++mf) {
        int rl0 = wm * 64 + mf * 16 + ((lane >> 4) << 2);
#pragma unroll
        for (int r = 0; r < 4; ++r) {
            int rl = rl0 + r;
            if (by * 128 + rl < n_e) {
#pragma unroll
                for (int nf = 0; nf < 2; ++nf) {
                    float g = ag[mf][nf][r];
                    float u = au[mf][nf][r];
                    float h = g / (1.f + __expf(-g)) * u;
                    hb[(size_t)(hbase + rl) * I_DIM + bx * 128 + wn * 32 + nf * 16 + l15] = (f16)h;
                }
            }
        }
    }
}

// ---------------- GEMM2: out[tok] += w * (h @ w2^T) ----------------
// Same template: BM=128 bucket rows, BN=256 out-cols, BK=64, per-wave 64x64.
__global__ __launch_bounds__(512, 2) void gemm2_kernel(
    const float* __restrict__ w2, const f16* __restrict__ hb, float* __restrict__ out,
    const int* __restrict__ counts, const int* __restrict__ offs,
    const int* __restrict__ btok, const float* __restrict__ bwv, int e_arg, int global_h)
{
    int e, bx, by;
    decode_panel(blockIdx.x, 8, e_arg, e, bx, by);
    const int n_e = counts[e];
    if (by * 128 >= n_e) return;
    const int boff = offs[e];
    const float* We = w2 + (size_t)e * H_DIM * I_DIM;

    const int tid  = threadIdx.x;
    const int lane = tid & 63;
    const int wid  = tid >> 6;
    const int wm   = wid >> 2;
    const int wn   = wid & 3;
    const int l15  = lane & 15;
    const int klo  = (lane >> 4) * 16;

    __shared__ f16 As[2][128 * 64];     // 16 KB per buffer
    __shared__ f16 Bs[2][256 * 64];     // 32 KB per buffer
    char* AsB = (char*)As; char* BsB = (char*)Bs;

    const int hb0 = global_h ? boff : 0;
    const f16* gA[2];
    int adst[2];
#pragma unroll
    for (int i = 0; i < 2; ++i) {
        int c = i * 512 + tid;
        int r = c >> 3;
        int idx = by * 128 + r;
        idx = idx < n_e ? idx : n_e - 1;
        gA[i] = hb + (size_t)(hb0 + idx) * I_DIM + ((c & 7) ^ (r & 7)) * 8;
        adst[i] = c * 16;
    }
    const float* gB[8];
    int bwadr[8];
#pragma unroll
    for (int j = 0; j < 8; ++j) {
        int c = j * 512 + tid;
        int row = c >> 4;
        int k4 = c & 15;
        gB[j] = We + (size_t)(bx * 256 + row) * I_DIM + k4 * 4;
        bwadr[j] = row * 128 + swzk(row, k4 * 8);
    }

    f32x4 acc[4][4];
#pragma unroll
    for (int m = 0; m < 4; ++m)
#pragma unroll
        for (int n = 0; n < 4; ++n) acc[m][n] = (f32x4)0.f;

    const int NT = I_DIM / 64;   // 88

    float4 bX[4], bY[4];
#pragma unroll
    for (int i = 0; i < 2; ++i)
        __builtin_amdgcn_global_load_lds((guint*)gA[i], (luint*)(AsB + adst[i]), 16, 0, 0);
#pragma unroll
    for (int j = 0; j < 4; ++j) bX[j] = *(const float4*)gB[j];
#pragma unroll
    for (int j = 0; j < 4; ++j) bY[j] = *(const float4*)gB[j + 4];
#pragma unroll
    for (int j = 0; j < 4; ++j) *(f16x4*)(BsB + bwadr[j])     = cvt4(bX[j]);
#pragma unroll
    for (int j = 0; j < 4; ++j) *(f16x4*)(BsB + bwadr[j + 4]) = cvt4(bY[j]);
#pragma unroll
    for (int j = 0; j < 4; ++j) bX[j] = *(const float4*)(gB[j] + 64);
#pragma unroll
    for (int j = 0; j < 4; ++j) bY[j] = *(const float4*)(gB[j + 4] + 64);
    asm volatile("s_waitcnt lgkmcnt(0)" ::: "memory");
    __builtin_amdgcn_s_barrier();

#pragma unroll 1
    for (int kt = 0; kt < NT; ++kt) {
        const int cur = kt & 1;
        const int kA = ((kt + 1 < NT) ? kt + 1 : NT - 1) * 64;
        const int kB = ((kt + 2 < NT) ? kt + 2 : NT - 1) * 64;
        const char* Ab = AsB + cur * 16384;
        const char* Bb = BsB + cur * 32768;
        char* Aw = AsB + (cur ^ 1) * 16384;
        char* Bw = BsB + (cur ^ 1) * 32768;
        // ================= phase 1: n-frags 0,1 =================
        {
#pragma unroll
            for (int i = 0; i < 2; ++i)
                __builtin_amdgcn_global_load_lds((guint*)(gA[i] + kA), (luint*)(Aw + adst[i]), 16, 0, 0);
            f16x8 af[2][4], bf[2][2];
#pragma unroll
            for (int kh = 0; kh < 2; ++kh) {
                const int kb = kh * 64 + klo;
#pragma unroll
                for (int mf = 0; mf < 4; ++mf) af[kh][mf] = ldsr(Ab, wm * 64 + mf * 16 + l15, kb);
#pragma unroll
                for (int nf = 0; nf < 2; ++nf) bf[kh][nf] = ldsr(Bb, wn * 64 + nf * 16 + l15, kb);
            }
#pragma unroll
            for (int j = 0; j < 4; ++j) *(f16x4*)(Bw + bwadr[j]) = cvt4(bX[j]);
            __builtin_amdgcn_s_barrier();
            LGKM0_SB();
            __builtin_amdgcn_s_setprio(1);
#pragma unroll
            for (int kh = 0; kh < 2; ++kh)
#pragma unroll
                for (int mf = 0; mf < 4; ++mf)
#pragma unroll
                    for (int nf = 0; nf < 2; ++nf)
                        acc[mf][nf] = __builtin_amdgcn_mfma_f32_16x16x32_f16(af[kh][mf], bf[kh][nf], acc[mf][nf], 0, 0, 0);
            __builtin_amdgcn_s_setprio(0);
            __builtin_amdgcn_s_barrier();
        }
        // ================= phase 2: n-frags 2,3 =================
        {
#pragma unroll
            for (int j = 0; j < 4; ++j) bX[j] = *(const float4*)(gB[j] + kB);
            f16x8 af[2][4], bf[2][2];
#pragma unroll
            for (int kh = 0; kh < 2; ++kh) {
                const int kb = kh * 64 + klo;
#pragma unroll
                for (int mf = 0; mf < 4; ++mf) af[kh][mf] = ldsr(Ab, wm * 64 + mf * 16 + l15, kb);
#pragma unroll
                for (int nf = 0; nf < 2; ++nf) bf[kh][nf] = ldsr(Bb, wn * 64 + (nf + 2) * 16 + l15, kb);
            }
#pragma unroll
            for (int j = 0; j < 4; ++j) *(f16x4*)(Bw + bwadr[j + 4]) = cvt4(bY[j]);
#pragma unroll
            for (int j = 0; j < 4; ++j) bY[j] = *(const float4*)(gB[j + 4] + kB);
            __builtin_amdgcn_s_barrier();
            LGKM0_SB();
            __builtin_amdgcn_s_setprio(1);
#pragma unroll
            for (int kh = 0; kh < 2; ++kh)
#pragma unroll
                for (int mf = 0; mf < 4; ++mf)
#pragma unroll
                    for (int nf = 0; nf < 2; ++nf)
                        acc[mf][nf + 2] = __builtin_amdgcn_mfma_f32_16x16x32_f16(af[kh][mf], bf[kh][nf], acc[mf][nf + 2], 0, 0, 0);
            __builtin_amdgcn_s_setprio(0);
            WAITVM8();
            __builtin_amdgcn_s_barrier();
        }
    }
    WAITVM0();

    // epilogue: weighted scatter-add
#pragma unroll
    for (int mf = 0; mf < 4; ++mf) {
        int rl0 = wm * 64 + mf * 16 + ((lane >> 4) << 2);
#pragma unroll
        for (int r = 0; r < 4; ++r) {
            int rl = rl0 + r;
            if (by * 128 + rl < n_e) {
                int p = boff + by * 128 + rl;
                int tok = btok[p];
                float w = bwv[p];
#pragma unroll
                for (int nf = 0; nf < 4; ++nf)
                    atomicAdd(&out[(size_t)tok * H_DIM + bx * 256 + wn * 64 + nf * 16 + l15],
                              w * acc[mf][nf][r]);
            }
        }
    }
}

extern "C" void kernel_launch(void* const* d_in, const int* in_sizes, int n_in,
                              void* d_out, int out_size, void* d_ws, size_t ws_size,
                              hipStream_t stream) {
    const float* hs  = (const float*)d_in[0];
    const float* gw  = (const float*)d_in[1];
    const float* w13 = (const float*)d_in[2];
    const float* w2  = (const float*)d_in[3];
    float* out = (float*)d_out;

    char* ws = (char*)d_ws;
    int*   meta = (int*)(ws + OFF_META);
    int*   btok = (int*)(ws + OFF_BTOK);
    float* bwv  = (float*)(ws + OFF_BW);
    int*   re   = (int*)(ws + OFF_RE);
    float* rw   = (float*)(ws + OFF_RW);
    f16*   hsb  = (f16*)(ws + OFF_HSB);
    f16*   hb   = (f16*)(ws + OFF_HB);

    hipMemsetAsync(d_out, 0, (size_t)T_TOK * H_DIM * 4, stream);
    hipMemsetAsync(meta, 0, 256, stream);

    cvt_hs_kernel<<<(T_TOK * H_DIM) / (256 * 8), 256, 0, stream>>>(hs, hsb);
    gate_kernel<<<T_TOK / 4, 256, 0, stream>>>(hs, gw, re, rw, meta);
    scan_kernel<<<1, 64, 0, stream>>>(meta);
    place_kernel<<<T_TOK / 256, 256, 0, stream>>>(re, rw, meta + 16, btok, bwv);

    size_t need_allpairs = OFF_HB + (size_t)(2 * T_TOK + 128) * I_DIM * 2;
    if (ws_size >= need_allpairs) {
        // gemm1: 8e x 44bx = 352 panels x 32 by; gemm2: 8e x 8bx = 64 panels x 32 by
        gemm1_kernel<<<352 * 32, 512, 0, stream>>>(w13, hsb, hb, meta, meta + 8, btok, -1, 1);
        gemm2_kernel<<<64 * 32, 512, 0, stream>>>(w2, hb, out, meta, meta + 8, btok, bwv, -1, 1);
    } else {
        for (int e = 0; e < NE; ++e) {
            gemm1_kernel<<<44 * 32, 512, 0, stream>>>(w13, hsb, hb, meta, meta + 8, btok, e, 0);
            gemm2_kernel<<<8 * 32, 512, 0, stream>>>(w2, hb, out, meta, meta + 8, btok, bwv, e, 0);
        }
    }
}

// Round 9
// 1278.464 us; speedup vs baseline: 1.2890x; 1.2890x over previous
//
#include <hip/hip_runtime.h>

#define T_TOK 4096
#define H_DIM 2048
#define I_DIM 5632
#define NE 8

typedef _Float16 f16;
typedef _Float16 f16x8 __attribute__((ext_vector_type(8)));
typedef float f32x4 __attribute__((ext_vector_type(4)));

// ---- workspace layout (byte offsets) ----
#define OFF_META   0                         // counts[8] | offs[8] | cursor[8]
#define OFF_BTOK   256
#define OFF_BW     (256 + 32768)
#define OFF_RE     (256 + 2 * 32768)
#define OFF_RW     (256 + 3 * 32768)
#define OFF_HSB    (256 + 4 * 32768)
#define OFF_WF     (OFF_HSB + (size_t)T_TOK * H_DIM * 2)   // f16 weight area starts here

typedef const __attribute__((address_space(1))) unsigned int guint;
typedef __attribute__((address_space(3))) unsigned int luint;

// 8-slot (16B) XOR swizzle within a 128-byte LDS row: conflict-free reads (verified R3-R8: 0 conflicts)
__device__ __forceinline__ int swzk(int r, int bir) {
    return (bir & 15) | ((((bir >> 4) ^ r) & 7) << 4);
}

// ---------------- f32 -> f16 streaming convert (weights) ----------------
__global__ void cvt_w_kernel(const float* __restrict__ src, f16* __restrict__ dst, int n8) {
    int stride = gridDim.x * blockDim.x;
    for (int i = blockIdx.x * blockDim.x + threadIdx.x; i < n8; i += stride) {
        size_t b = (size_t)i * 8;
        float4 a = *(const float4*)(src + b);
        float4 c = *(const float4*)(src + b + 4);
        f16x8 v;
        v[0] = (f16)a.x; v[1] = (f16)a.y; v[2] = (f16)a.z; v[3] = (f16)a.w;
        v[4] = (f16)c.x; v[5] = (f16)c.y; v[6] = (f16)c.z; v[7] = (f16)c.w;
        *(f16x8*)(dst + b) = v;
    }
}

// ---------------- hs f32 -> f16 ----------------
__global__ void cvt_hs_kernel(const float* __restrict__ hs, f16* __restrict__ hsb) {
    size_t i = ((size_t)blockIdx.x * 256 + threadIdx.x) * 8;
    float4 a = *(const float4*)(hs + i);
    float4 b = *(const float4*)(hs + i + 4);
    f16x8 v;
    v[0] = (f16)a.x; v[1] = (f16)a.y; v[2] = (f16)a.z; v[3] = (f16)a.w;
    v[4] = (f16)b.x; v[5] = (f16)b.y; v[6] = (f16)b.z; v[7] = (f16)b.w;
    *(f16x8*)(hsb + i) = v;
}

// ---------------- gating ----------------
__global__ void gate_kernel(const float* __restrict__ hs, const float* __restrict__ gw,
                            int* __restrict__ re, float* __restrict__ rw,
                            int* __restrict__ counts) {
    int lane = threadIdx.x & 63;
    int t = blockIdx.x * 4 + (threadIdx.x >> 6);
    float acc[NE];
#pragma unroll
    for (int e = 0; e < NE; ++e) acc[e] = 0.f;
    const float* x = hs + (size_t)t * H_DIM;
    for (int i = lane; i < H_DIM; i += 64) {
        float xv = x[i];
#pragma unroll
        for (int e = 0; e < NE; ++e) acc[e] += xv * gw[e * H_DIM + i];
    }
#pragma unroll
    for (int e = 0; e < NE; ++e)
        for (int off = 32; off > 0; off >>= 1) acc[e] += __shfl_xor(acc[e], off);
    if (lane == 0) {
        int i1 = 0; float l1 = acc[0];
#pragma unroll
        for (int e = 1; e < NE; ++e) if (acc[e] > l1) { l1 = acc[e]; i1 = e; }
        int i2 = -1; float l2 = -1e30f;
#pragma unroll
        for (int e = 0; e < NE; ++e) if (e != i1 && acc[e] > l2) { l2 = acc[e]; i2 = e; }
        float aa = __expf(l2 - l1);
        float s = 1.f / (1.f + aa);
        re[t * 2] = i1; re[t * 2 + 1] = i2;
        rw[t * 2] = s;  rw[t * 2 + 1] = aa * s;
        atomicAdd(&counts[i1], 1);
        atomicAdd(&counts[i2], 1);
    }
}

__global__ void scan_kernel(int* __restrict__ meta) {
    if (threadIdx.x == 0) {
        int s = 0;
        for (int e = 0; e < NE; ++e) { meta[8 + e] = s; meta[16 + e] = s; s += meta[e]; }
    }
}

__global__ void place_kernel(const int* __restrict__ re, const float* __restrict__ rw,
                             int* __restrict__ cursor, int* __restrict__ btok,
                             float* __restrict__ bwv) {
    int t = blockIdx.x * 256 + threadIdx.x;
    if (t >= T_TOK) return;
#pragma unroll
    for (int s = 0; s < 2; ++s) {
        int e = re[t * 2 + s];
        int p = atomicAdd(&cursor[e], 1);
        btok[p] = t;
        bwv[p] = rw[t * 2 + s];
    }
}

// Panel-pinned XCD decode (validated R3/R4): panel P = sg*8 + (id&7) lives entirely on
// XCD id%8 (its 32 by-blocks are ids sg*256 + by*8 + x, all congruent mod 8).
__device__ __forceinline__ void decode_panel(int id, int npx, int e_arg,
                                             int& e, int& bx, int& by) {
    if (e_arg >= 0) { e = e_arg; bx = id >> 5; by = id & 31; return; }
    int sg  = id >> 8;
    int rem = id & 255;
    by = rem >> 3;
    int P = sg * 8 + (rem & 7);
    e = P / npx; bx = P % npx;
}

// ---------------- GEMM1: h = silu(X@Wg^T) * (X@Wu^T) ----------------
// All-DMA staging (f16 weights), catalog T3-minimum loop: one __syncthreads per tile
// (compiler's vmcnt(0) there retires last tile's DMAs after a full compute phase of
// flight), then issue DMA(t+1) into the freed buffer, then ds_read + 32 MFMA.
// BM=128 tokens x 64 h-cols (Bg rows 0-63, Bu rows 64-127), BK=64, 256 thr / 4 waves
// (2m x 2n), wave = 64 rows x (32 g + 32 u): 8 ds_reads feed 16 MFMAs (rho=0.5).
// LDS 64 KB dbuf -> 2 blocks/CU. Zero inline asm.
__global__ __launch_bounds__(256, 2) void gemm1_kernel(
    const f16* __restrict__ w13f, const f16* __restrict__ hsb, f16* __restrict__ hb,
    const int* __restrict__ counts, const int* __restrict__ offs,
    const int* __restrict__ btok, int e_arg, int global_h)
{
    int e, bx, by;
    decode_panel(blockIdx.x, 88, e_arg, e, bx, by);
    const int n_e = counts[e];
    if (by * 128 >= n_e) return;
    const int boff = offs[e];
    const f16* We = (e_arg >= 0) ? w13f : (w13f + (size_t)e * (2 * I_DIM) * H_DIM);

    const int tid = threadIdx.x;
    const int lane = tid & 63;
    const int wid = tid >> 6;
    const int wm = wid >> 1, wn = wid & 1;
    const int l15 = lane & 15;

    __shared__ f16 As0[128 * 64], As1[128 * 64];   // 16 KB each
    __shared__ f16 Bs0[128 * 64], Bs1[128 * 64];   // 16 KB each

    // DMA sources: chunk c = i*256+tid -> LDS row c>>3, slot c&7 (dest linear c*16);
    // global k-slot = (c&7)^(r&7): inverse of the read swizzle (verified R5+).
    const f16* gA[4]; const f16* gB[4]; int dstc[4];
#pragma unroll
    for (int i = 0; i < 4; ++i) {
        int c = i * 256 + tid;
        int r = c >> 3;
        dstc[i] = c * 16;
        int slot = ((c & 7) ^ (r & 7)) * 8;
        int idx = by * 128 + r;
        idx = idx < n_e ? idx : n_e - 1;
        gA[i] = hsb + (size_t)btok[boff + idx] * H_DIM + slot;
        int wrow = (r < 64) ? (bx * 64 + r) : (I_DIM + bx * 64 + (r - 64));
        gB[i] = We + (size_t)wrow * H_DIM + slot;
    }

    f32x4 ag[4][2], au[4][2];
#pragma unroll
    for (int m = 0; m < 4; ++m)
#pragma unroll
        for (int n = 0; n < 2; ++n) { ag[m][n] = (f32x4)0.f; au[m][n] = (f32x4)0.f; }

    const int NT = H_DIM / 64;   // 32 (even)

    // prologue: tile 0 -> buf0
#pragma unroll
    for (int i = 0; i < 4; ++i) {
        __builtin_amdgcn_global_load_lds((guint*)gA[i], (luint*)((char*)As0 + dstc[i]), 16, 0, 0);
        __builtin_amdgcn_global_load_lds((guint*)gB[i], (luint*)((char*)Bs0 + dstc[i]), 16, 0, 0);
    }

#define G1T(AR, BR, AW, BW, t)                                                      \
    {                                                                               \
        __syncthreads();   /* drains tile-t DMAs (in flight one full phase); frees AW/BW */ \
        if ((t) + 1 < NT) {                                                         \
            const int k0 = ((t) + 1) * 64;                                          \
            _Pragma("unroll")                                                       \
            for (int i = 0; i < 4; ++i) {                                           \
                __builtin_amdgcn_global_load_lds((guint*)(gA[i] + k0),              \
                    (luint*)((char*)AW + dstc[i]), 16, 0, 0);                       \
                __builtin_amdgcn_global_load_lds((guint*)(gB[i] + k0),              \
                    (luint*)((char*)BW + dstc[i]), 16, 0, 0);                       \
            }                                                                       \
        }                                                                           \
        _Pragma("unroll")                                                           \
        for (int kh = 0; kh < 2; ++kh) {                                            \
            const int kb = kh * 64 + (lane >> 4) * 16;                              \
            f16x8 a[4], bg[2], bu[2];                                               \
            _Pragma("unroll")                                                       \
            for (int m = 0; m < 4; ++m) {                                           \
                int r = wm * 64 + m * 16 + l15;                                     \
                a[m] = *(const f16x8*)((const char*)AR + r * 128 + swzk(r, kb));    \
            }                                                                       \
            _Pragma("unroll")                                                       \
            for (int n = 0; n < 2; ++n) {                                           \
                int rg = wn * 32 + n * 16 + l15;                                    \
                bg[n] = *(const f16x8*)((const char*)BR + rg * 128 + swzk(rg, kb)); \
                int ru = 64 + rg;                                                   \
                bu[n] = *(const f16x8*)((const char*)BR + ru * 128 + swzk(ru, kb)); \
            }                                                                       \
            _Pragma("unroll")                                                       \
            for (int m = 0; m < 4; ++m)                                             \
                _Pragma("unroll")                                                   \
                for (int n = 0; n < 2; ++n) {                                       \
                    ag[m][n] = __builtin_amdgcn_mfma_f32_16x16x32_f16(a[m], bg[n], ag[m][n], 0, 0, 0); \
                    au[m][n] = __builtin_amdgcn_mfma_f32_16x16x32_f16(a[m], bu[n], au[m][n], 0, 0, 0); \
                }                                                                   \
        }                                                                           \
    }

#pragma unroll 1
    for (int kt = 0; kt < NT; kt += 2) {
        G1T(As0, Bs0, As1, Bs1, kt);
        G1T(As1, Bs1, As0, Bs0, kt + 1);
    }
#undef G1T

    // epilogue: silu(g)*u -> f16 h
    const int hbase = (global_h ? boff : 0) + by * 128;
#pragma unroll
    for (int m = 0; m < 4; ++m) {
        int rl0 = wm * 64 + m * 16 + ((lane >> 4) << 2);
#pragma unroll
        for (int r = 0; r < 4; ++r) {
            int rl = rl0 + r;
            if (by * 128 + rl < n_e) {
#pragma unroll
                for (int n = 0; n < 2; ++n) {
                    float g = ag[m][n][r];
                    float u = au[m][n][r];
                    float h = g / (1.f + __expf(-g)) * u;
                    hb[(size_t)(hbase + rl) * I_DIM + bx * 64 + wn * 32 + n * 16 + l15] = (f16)h;
                }
            }
        }
    }
}

// ---------------- GEMM2: out[tok] += w * (h @ w2^T) ----------------
// Same structure: BM=128 x BN=128, BK=64, 4 waves (2x2), wave 64x64 (rho=0.5).
__global__ __launch_bounds__(256, 2) void gemm2_kernel(
    const f16* __restrict__ w2f, const f16* __restrict__ hb, float* __restrict__ out,
    const int* __restrict__ counts, const int* __restrict__ offs,
    const int* __restrict__ btok, const float* __restrict__ bwv, int e_arg, int global_h)
{
    int e, bx, by;
    decode_panel(blockIdx.x, 16, e_arg, e, bx, by);
    const int n_e = counts[e];
    if (by * 128 >= n_e) return;
    const int boff = offs[e];
    const f16* We = (e_arg >= 0) ? w2f : (w2f + (size_t)e * H_DIM * I_DIM);

    const int tid = threadIdx.x;
    const int lane = tid & 63;
    const int wid = tid >> 6;
    const int wm = wid >> 1, wn = wid & 1;
    const int l15 = lane & 15;

    __shared__ f16 As0[128 * 64], As1[128 * 64];
    __shared__ f16 Bs0[128 * 64], Bs1[128 * 64];

    const int hb0 = global_h ? boff : 0;
    const f16* gA[4]; const f16* gB[4]; int dstc[4];
#pragma unroll
    for (int i = 0; i < 4; ++i) {
        int c = i * 256 + tid;
        int r = c >> 3;
        dstc[i] = c * 16;
        int slot = ((c & 7) ^ (r & 7)) * 8;
        int idx = by * 128 + r;
        idx = idx < n_e ? idx : n_e - 1;
        gA[i] = hb + (size_t)(hb0 + idx) * I_DIM + slot;
        gB[i] = We + (size_t)(bx * 128 + r) * I_DIM + slot;
    }

    f32x4 acc[4][4];
#pragma unroll
    for (int m = 0; m < 4; ++m)
#pragma unroll
        for (int n = 0; n < 4; ++n) acc[m][n] = (f32x4)0.f;

    const int NT = I_DIM / 64;   // 88 (even)

#pragma unroll
    for (int i = 0; i < 4; ++i) {
        __builtin_amdgcn_global_load_lds((guint*)gA[i], (luint*)((char*)As0 + dstc[i]), 16, 0, 0);
        __builtin_amdgcn_global_load_lds((guint*)gB[i], (luint*)((char*)Bs0 + dstc[i]), 16, 0, 0);
    }

#define G2T(AR, BR, AW, BW, t)                                                      \
    {                                                                               \
        __syncthreads();                                                            \
        if ((t) + 1 < NT) {                                                         \
            const int k0 = ((t) + 1) * 64;                                          \
            _Pragma("unroll")                                                       \
            for (int i = 0; i < 4; ++i) {                                           \
                __builtin_amdgcn_global_load_lds((guint*)(gA[i] + k0),              \
                    (luint*)((char*)AW + dstc[i]), 16, 0, 0);                       \
                __builtin_amdgcn_global_load_lds((guint*)(gB[i] + k0),              \
                    (luint*)((char*)BW + dstc[i]), 16, 0, 0);                       \
            }                                                                       \
        }                                                                           \
        _Pragma("unroll")                                                           \
        for (int kh = 0; kh < 2; ++kh) {                                            \
            const int kb = kh * 64 + (lane >> 4) * 16;                              \
            f16x8 a[4], b[4];                                                       \
            _Pragma("unroll")                                                       \
            for (int m = 0; m < 4; ++m) {                                           \
                int r = wm * 64 + m * 16 + l15;                                     \
                a[m] = *(const f16x8*)((const char*)AR + r * 128 + swzk(r, kb));    \
            }                                                                       \
            _Pragma("unroll")                                                       \
            for (int n = 0; n < 4; ++n) {                                           \
                int r = wn * 64 + n * 16 + l15;                                     \
                b[n] = *(const f16x8*)((const char*)BR + r * 128 + swzk(r, kb));    \
            }                                                                       \
            _Pragma("unroll")                                                       \
            for (int m = 0; m < 4; ++m)                                             \
                _Pragma("unroll")                                                   \
                for (int n = 0; n < 4; ++n)                                         \
                    acc[m][n] = __builtin_amdgcn_mfma_f32_16x16x32_f16(a[m], b[n], acc[m][n], 0, 0, 0); \
        }                                                                           \
    }

#pragma unroll 1
    for (int kt = 0; kt < NT; kt += 2) {
        G2T(As0, Bs0, As1, Bs1, kt);
        G2T(As1, Bs1, As0, Bs0, kt + 1);
    }
#undef G2T

    // epilogue: weighted scatter-add
#pragma unroll
    for (int m = 0; m < 4; ++m) {
        int rl0 = wm * 64 + m * 16 + ((lane >> 4) << 2);
#pragma unroll
        for (int r = 0; r < 4; ++r) {
            int rl = rl0 + r;
            if (by * 128 + rl < n_e) {
                int p = boff + by * 128 + rl;
                int tok = btok[p];
                float w = bwv[p];
#pragma unroll
                for (int n = 0; n < 4; ++n)
                    atomicAdd(&out[(size_t)tok * H_DIM + bx * 128 + wn * 64 + n * 16 + l15],
                              w * acc[m][n][r]);
            }
        }
    }
}

extern "C" void kernel_launch(void* const* d_in, const int* in_sizes, int n_in,
                              void* d_out, int out_size, void* d_ws, size_t ws_size,
                              hipStream_t stream) {
    const float* hs  = (const float*)d_in[0];
    const float* gw  = (const float*)d_in[1];
    const float* w13 = (const float*)d_in[2];
    const float* w2  = (const float*)d_in[3];
    float* out = (float*)d_out;

    char* ws = (char*)d_ws;
    int*   meta = (int*)(ws + OFF_META);
    int*   btok = (int*)(ws + OFF_BTOK);
    float* bwv  = (float*)(ws + OFF_BW);
    int*   re   = (int*)(ws + OFF_RE);
    float* rw   = (float*)(ws + OFF_RW);
    f16*   hsb  = (f16*)(ws + OFF_HSB);

    hipMemsetAsync(d_out, 0, (size_t)T_TOK * H_DIM * 4, stream);
    hipMemsetAsync(meta, 0, 256, stream);

    cvt_hs_kernel<<<(T_TOK * H_DIM) / (256 * 8), 256, 0, stream>>>(hs, hsb);
    gate_kernel<<<T_TOK / 4, 256, 0, stream>>>(hs, gw, re, rw, meta);
    scan_kernel<<<1, 64, 0, stream>>>(meta);
    place_kernel<<<T_TOK / 256, 256, 0, stream>>>(re, rw, meta + 16, btok, bwv);

    const size_t w13_elems = (size_t)NE * 2 * I_DIM * H_DIM;   // 184,549,376
    const size_t w2_elems  = (size_t)NE * H_DIM * I_DIM;       //  92,274,688

    // full-f16 path layout
    size_t o_w13f = OFF_WF;
    size_t o_w2f  = o_w13f + w13_elems * 2;
    size_t o_hb   = o_w2f + w2_elems * 2;
    size_t need_full = o_hb + (size_t)2 * T_TOK * I_DIM * 2;

    // per-expert fallback layout
    size_t f_w13 = OFF_WF;
    size_t f_w2  = f_w13 + (size_t)2 * I_DIM * H_DIM * 2;
    size_t f_hb  = f_w2 + (size_t)H_DIM * I_DIM * 2;
    size_t need_pe = f_hb + (size_t)T_TOK * I_DIM * 2;
    (void)need_pe;

    if (ws_size >= need_full) {
        f16* w13f = (f16*)(ws + o_w13f);
        f16* w2f  = (f16*)(ws + o_w2f);
        f16* hb   = (f16*)(ws + o_hb);
        cvt_w_kernel<<<2048, 256, 0, stream>>>(w13, w13f, (int)(w13_elems / 8));
        cvt_w_kernel<<<2048, 256, 0, stream>>>(w2,  w2f,  (int)(w2_elems / 8));
        // gemm1: 8e x 88bx = 704 panels x 32 by; gemm2: 8e x 16bx = 128 panels x 32 by
        gemm1_kernel<<<704 * 32, 256, 0, stream>>>(w13f, hsb, hb, meta, meta + 8, btok, -1, 1);
        gemm2_kernel<<<128 * 32, 256, 0, stream>>>(w2f, hb, out, meta, meta + 8, btok, bwv, -1, 1);
    } else {
        f16* w13f = (f16*)(ws + f_w13);
        f16* w2f  = (f16*)(ws + f_w2);
        f16* hb   = (f16*)(ws + f_hb);
        for (int e = 0; e < NE; ++e) {
            cvt_w_kernel<<<1024, 256, 0, stream>>>(w13 + (size_t)e * 2 * I_DIM * H_DIM, w13f,
                                                   (int)((size_t)2 * I_DIM * H_DIM / 8));
            gemm1_kernel<<<88 * 32, 256, 0, stream>>>(w13f, hsb, hb, meta, meta + 8, btok, e, 0);
            cvt_w_kernel<<<1024, 256, 0, stream>>>(w2 + (size_t)e * H_DIM * I_DIM, w2f,
                                                   (int)((size_t)H_DIM * I_DIM / 8));
            gemm2_kernel<<<16 * 32, 256, 0, stream>>>(w2f, hb, out, meta, meta + 8, btok, bwv, e, 0);
        }
    }
}